// Round 1
// baseline (382.468 us; speedup 1.0000x reference)
//
#include <hip/hip_runtime.h>
#include <math.h>

#define BB   256   // batch
#define CC   512   // channels
#define HWN  196   // 14*14
#define CH   56    // hw rows per chunk
#define NR   7     // rows per thread per chunk (CH / 8 waves)
#define KC   16    // c per LDS stage
#define TPAD 20    // tile row pitch in floats (16 + pad, keeps 16B align)
#define TAUC 0.03f
#define EPSC 0.65f
#define EPS2C 0.4f
#define RLT  (1.0f/0.07f)

// out layout (flat, fp32):
//   A      [256,1,14,14] @ 0       (50176)
//   logits [256,258]     @ 50176   (66048)
//   Pos    [256,1,14,14] @ 116224  (50176)
//   Neg    [256,1,14,14] @ 166400  (50176)
//   A0_ref [256,256]     @ 216576  (65536)

__global__ __launch_bounds__(256) void prep_aud(const float* __restrict__ aud,
                                                float* __restrict__ aud_t) {
    int n = blockIdx.x;
    int t = threadIdx.x;
    float a0 = aud[n * CC + t];
    float a1 = aud[n * CC + 256 + t];
    float s = a0 * a0 + a1 * a1;
    #pragma unroll
    for (int off = 32; off; off >>= 1) s += __shfl_down(s, off, 64);
    __shared__ float ws[4];
    __shared__ float rns;
    if ((t & 63) == 0) ws[t >> 6] = s;
    __syncthreads();
    if (t == 0) {
        float tot = ws[0] + ws[1] + ws[2] + ws[3];
        rns = 1.0f / fmaxf(sqrtf(tot), 1e-12f);
    }
    __syncthreads();
    float rn = rns;
    // transposed layout aud_t[c][m]
    aud_t[t * BB + n]         = a0 * rn;
    aud_t[(256 + t) * BB + n] = a1 * rn;
}

__global__ __launch_bounds__(512) void av_main(const float* __restrict__ img,
                                               const float* __restrict__ aud_t,
                                               float* __restrict__ out) {
    const int n   = blockIdx.x;
    const int tid = threadIdx.x;
    const int w   = tid >> 6;   // wave 0..7
    const int l   = tid & 63;   // lane
    const int m0  = l << 2;     // columns m0..m0+3

    __shared__ float tile[CH * TPAD];
    __shared__ float rnorm_s[CH];
    __shared__ float red_max[8][BB];
    __shared__ float red_sw[8][BB];
    __shared__ float red_swa[8][BB];
    __shared__ float red_diag[8][4];

    const float* imgn = img + (size_t)n * (CC * HWN);
    const float4* aud4 = (const float4*)aud_t;

    float maxv[4], sw[4], swa[4];
    #pragma unroll
    for (int j = 0; j < 4; j++) { maxv[j] = -1e30f; sw[j] = 0.f; swa[j] = 0.f; }
    float s1n = 0.f, s1d = 0.f, s2n = 0.f, s2d = 0.f;
    const int diag_l = n >> 2, diag_j = n & 3;

    float* outA = out;
    float* outL = out + 50176;
    float* outP = out + 116224;
    float* outN = out + 166400;
    float* outR = out + 216576;

    for (int hw0 = 0; hw0 < HWN; hw0 += CH) {
        float acc[NR][4];
        #pragma unroll
        for (int r = 0; r < NR; r++)
            #pragma unroll
            for (int j = 0; j < 4; j++) acc[r][j] = 0.f;
        float nrm = 0.f;

        for (int c0 = 0; c0 < CC; c0 += KC) {
            __syncthreads();   // previous tile consumers done
            // stage img[n, c0:c0+16, hw0:hw0+56] -> tile[hw][cj]
            for (int e = tid; e < KC * CH; e += 512) {
                int cj = e / CH;
                int hw = e - cj * CH;
                int g  = hw0 + hw;
                float v = (g < HWN) ? imgn[(c0 + cj) * HWN + g] : 0.f;
                tile[hw * TPAD + cj] = v;
            }
            __syncthreads();

            // norm partial sums (wave 0, one thread per row)
            if (tid < CH) {
                #pragma unroll
                for (int cg = 0; cg < 4; cg++) {
                    float4 v = *(const float4*)&tile[tid * TPAD + cg * 4];
                    nrm += v.x * v.x + v.y * v.y + v.z * v.z + v.w * v.w;
                }
            }

            // GEMM micro-tile: 7 rows x 4 cols x 16 c
            #pragma unroll
            for (int cg = 0; cg < 4; cg++) {
                const int cb = (c0 + cg * 4) * 64 + l;
                float4 av0 = aud4[cb];
                float4 av1 = aud4[cb + 64];
                float4 av2 = aud4[cb + 128];
                float4 av3 = aud4[cb + 192];
                #pragma unroll
                for (int r = 0; r < NR; r++) {
                    const float4 iv = *(const float4*)&tile[(r * 8 + w) * TPAD + cg * 4];
                    acc[r][0] = fmaf(iv.x, av0.x, acc[r][0]);
                    acc[r][1] = fmaf(iv.x, av0.y, acc[r][1]);
                    acc[r][2] = fmaf(iv.x, av0.z, acc[r][2]);
                    acc[r][3] = fmaf(iv.x, av0.w, acc[r][3]);
                    acc[r][0] = fmaf(iv.y, av1.x, acc[r][0]);
                    acc[r][1] = fmaf(iv.y, av1.y, acc[r][1]);
                    acc[r][2] = fmaf(iv.y, av1.z, acc[r][2]);
                    acc[r][3] = fmaf(iv.y, av1.w, acc[r][3]);
                    acc[r][0] = fmaf(iv.z, av2.x, acc[r][0]);
                    acc[r][1] = fmaf(iv.z, av2.y, acc[r][1]);
                    acc[r][2] = fmaf(iv.z, av2.z, acc[r][2]);
                    acc[r][3] = fmaf(iv.z, av2.w, acc[r][3]);
                    acc[r][0] = fmaf(iv.w, av3.x, acc[r][0]);
                    acc[r][1] = fmaf(iv.w, av3.y, acc[r][1]);
                    acc[r][2] = fmaf(iv.w, av3.z, acc[r][2]);
                    acc[r][3] = fmaf(iv.w, av3.w, acc[r][3]);
                }
            }
        }

        if (tid < CH) rnorm_s[tid] = 1.0f / fmaxf(sqrtf(nrm), 1e-12f);
        __syncthreads();

        // fused epilogue for this hw chunk
        #pragma unroll
        for (int r = 0; r < NR; r++) {
            int rl = r * 8 + w;
            int g  = hw0 + rl;
            if (g < HWN) {
                float rn = rnorm_s[rl];
                #pragma unroll
                for (int j = 0; j < 4; j++) {
                    float a0 = acc[r][j] * rn;
                    float wg = 1.0f / (1.0f + expf((EPSC - a0) / TAUC)); // sigmoid((a0-EPS)/TAU)
                    maxv[j] = fmaxf(maxv[j], a0);
                    sw[j]  += wg;
                    swa[j] += wg * a0;
                    if (l == diag_l && j == diag_j) {
                        outA[n * HWN + g] = a0;
                        outP[n * HWN + g] = wg;
                        float p2  = 1.0f / (1.0f + expf((EPS2C - a0) / TAUC));
                        float neg = 1.0f - p2;
                        outN[n * HWN + g] = neg;
                        s1n += wg * a0; s1d += wg;
                        s2n += neg * a0; s2d += neg;
                    }
                }
            }
        }
    }

    // cross-wave reduction
    #pragma unroll
    for (int j = 0; j < 4; j++) {
        red_max[w][m0 + j] = maxv[j];
        red_sw[w][m0 + j]  = sw[j];
        red_swa[w][m0 + j] = swa[j];
    }
    if (l == diag_l) {
        red_diag[w][0] = s1n; red_diag[w][1] = s1d;
        red_diag[w][2] = s2n; red_diag[w][3] = s2d;
    }
    __syncthreads();

    if (tid < BB) {
        int m = tid;
        float mx = -1e30f, num = 0.f, den = 0.f;
        #pragma unroll
        for (int ww = 0; ww < 8; ww++) {
            mx  = fmaxf(mx, red_max[ww][m]);
            num += red_swa[ww][m];
            den += red_sw[ww][m];
        }
        float sim = num / den;
        if (m == n) sim *= -99.0f;
        outL[n * 258 + 1 + m] = sim * RLT;
        outR[n * BB + m] = mx;
        if (m == n) {
            float t1n = 0.f, t1d = 0.f, t2n = 0.f, t2d = 0.f;
            #pragma unroll
            for (int ww = 0; ww < 8; ww++) {
                t1n += red_diag[ww][0]; t1d += red_diag[ww][1];
                t2n += red_diag[ww][2]; t2d += red_diag[ww][3];
            }
            outL[n * 258 + 0]   = (t1n / t1d) * RLT;
            outL[n * 258 + 257] = (t2n / t2d) * RLT;
        }
    }
}

extern "C" void kernel_launch(void* const* d_in, const int* in_sizes, int n_in,
                              void* d_out, int out_size, void* d_ws, size_t ws_size,
                              hipStream_t stream) {
    const float* img = (const float*)d_in[0];
    const float* aud = (const float*)d_in[1];
    float* out = (float*)d_out;
    float* aud_t = (float*)d_ws;   // 512*256 floats = 512 KB

    prep_aud<<<BB, 256, 0, stream>>>(aud, aud_t);
    av_main<<<BB, 512, 0, stream>>>(img, aud_t, out);
}

// Round 2
// 47.690 us; speedup vs baseline: 8.0199x; 8.0199x over previous
//
#include <hip/hip_runtime.h>
#include <math.h>

typedef _Float16 half8 __attribute__((ext_vector_type(8)));
typedef float f32x4 __attribute__((ext_vector_type(4)));

#define HWN 196
#define RLT (1.0f/0.07f)

// out layout (flat fp32):
//   A      [256,196]  @ 0
//   logits [256,258]  @ 50176
//   Pos    [256,196]  @ 116224
//   Neg    [256,196]  @ 166400
//   A0_ref [256,256]  @ 216576

// aud_pk layout: [c>>3][m][c&7] fp16, i.e. 64 groups x 256 m x 8 halves (16B per (cg,m))
__global__ __launch_bounds__(256) void prep_aud_pk(const float* __restrict__ aud,
                                                   _Float16* __restrict__ aud_pk) {
    int m = blockIdx.x, t = threadIdx.x;
    float a0 = aud[m * 512 + t];
    float a1 = aud[m * 512 + 256 + t];
    float s = a0 * a0 + a1 * a1;
    #pragma unroll
    for (int off = 32; off; off >>= 1) s += __shfl_down(s, off, 64);
    __shared__ float wsum[4];
    __shared__ float rns;
    if ((t & 63) == 0) wsum[t >> 6] = s;
    __syncthreads();
    if (t == 0) rns = 1.0f / fmaxf(sqrtf(wsum[0] + wsum[1] + wsum[2] + wsum[3]), 1e-12f);
    __syncthreads();
    float rn = rns;
    int c0 = t, c1 = t + 256;
    aud_pk[(c0 >> 3) * 2048 + m * 8 + (c0 & 7)] = (_Float16)(a0 * rn);
    aud_pk[(c1 >> 3) * 2048 + m * 8 + (c1 & 7)] = (_Float16)(a1 * rn);
}

__global__ __launch_bounds__(512, 2) void av_mfma(const float* __restrict__ img,
                                                  const _Float16* __restrict__ aud_pk,
                                                  float* __restrict__ out) {
    const int n = blockIdx.x;
    const int tid = threadIdx.x;
    const int w = tid >> 6, l = tid & 63;
    const int q = w & 3;        // m-quarter: cols 64q..64q+63
    const int hh = w >> 2;      // hw half: 0 -> rows 0..111 (7 tiles), 1 -> 112..207 (6 tiles)
    const int HT = hh ? 6 : 7;

    __shared__ _Float16 __align__(16) Abuf[2][4][208][8];  // [buf][kg][hw][j]
    __shared__ _Float16 __align__(16) Bbuf[2][4][256][8];  // [buf][kg][m][j]
    __shared__ float rnorm_s[208];
    __shared__ float nrm_parts[2][196];
    __shared__ float red_max[2][256], red_sw[2][256], red_swa[2][256];
    __shared__ float diag_parts[2][4][4];

    // zero the pad rows (196..207) of both A buffers once
    if (tid < 96) {
        int b = tid / 48, rem = tid % 48, kg = rem / 12, row = 196 + rem % 12;
        *(float4*)&Abuf[b][kg][row][0] = make_float4(0.f, 0.f, 0.f, 0.f);
    }

    const float* imgn = img + (size_t)n * (512 * 196);
    const bool act = tid < 392;            // staging threads: fixed hw each
    const int cl  = act ? tid / 196 : 0;   // c parity lane
    const int hws = act ? tid % 196 : 0;
    float nrm = 0.f;

    float  av[16];
    float4 bv[2];

    // ---- prologue: stage K-step 0 into buf 0
    {
        if (act) {
            #pragma unroll
            for (int i = 0; i < 16; i++) av[i] = imgn[(cl + 2 * i) * 196 + hws];
        }
        const float4* bs = (const float4*)aud_pk + tid;
        bv[0] = bs[0]; bv[1] = bs[512];
        if (act) {
            #pragma unroll
            for (int i = 0; i < 16; i++) {
                int c = cl + 2 * i;
                nrm += av[i] * av[i];
                Abuf[0][c >> 3][hws][c & 7] = (_Float16)av[i];
            }
        }
        ((float4*)&Bbuf[0][0][0][0])[tid]       = bv[0];
        ((float4*)&Bbuf[0][0][0][0])[tid + 512] = bv[1];
    }
    __syncthreads();

    f32x4 acc[7][4];
    #pragma unroll
    for (int ht = 0; ht < 7; ht++)
        #pragma unroll
        for (int mt = 0; mt < 4; mt++)
            acc[ht][mt] = (f32x4){0.f, 0.f, 0.f, 0.f};

    // per-lane LDS fragment offsets (in halves)
    const int aoff = (l >> 4) * 1664 + (hh * 112 + (l & 15)) * 8;  // + ht*128
    const int boff = (l >> 4) * 2048 + (q * 64 + (l & 15)) * 8;    // + mt*128

    for (int t = 0; t < 16; t++) {
        const int cur = t & 1;
        const bool more = t < 15;
        // issue global loads for next K-step early (hide under MFMA)
        if (more) {
            const float* src = imgn + (t + 1) * 32 * 196;
            if (act) {
                #pragma unroll
                for (int i = 0; i < 16; i++) av[i] = src[(cl + 2 * i) * 196 + hws];
            }
            const float4* bs = (const float4*)aud_pk + (t + 1) * 1024 + tid;
            bv[0] = bs[0]; bv[1] = bs[512];
        }
        // compute current K-step
        {
            const _Float16* Ab = &Abuf[cur][0][0][0];
            const _Float16* Bb = &Bbuf[cur][0][0][0];
            half8 bfrag[4];
            #pragma unroll
            for (int mt = 0; mt < 4; mt++) bfrag[mt] = *(const half8*)(Bb + boff + mt * 128);
            half8 afrag[7];
            #pragma unroll
            for (int ht = 0; ht < 7; ht++)
                if (ht < HT) afrag[ht] = *(const half8*)(Ab + aoff + ht * 128);
            #pragma unroll
            for (int ht = 0; ht < 7; ht++)
                if (ht < HT)
                    #pragma unroll
                    for (int mt = 0; mt < 4; mt++)
                        acc[ht][mt] = __builtin_amdgcn_mfma_f32_16x16x32_f16(
                            afrag[ht], bfrag[mt], acc[ht][mt], 0, 0, 0);
        }
        // write staged data into the other buffer
        if (more) {
            const int nb = cur ^ 1;
            if (act) {
                #pragma unroll
                for (int i = 0; i < 16; i++) {
                    int c = cl + 2 * i;
                    nrm += av[i] * av[i];
                    Abuf[nb][c >> 3][hws][c & 7] = (_Float16)av[i];
                }
            }
            ((float4*)&Bbuf[nb][0][0][0])[tid]       = bv[0];
            ((float4*)&Bbuf[nb][0][0][0])[tid + 512] = bv[1];
        }
        __syncthreads();
    }

    // ---- img row norms
    if (act) nrm_parts[cl][hws] = nrm;
    __syncthreads();
    if (tid < 208) {
        float v = 0.f;
        if (tid < 196) {
            float s = nrm_parts[0][tid] + nrm_parts[1][tid];
            v = 1.0f / fmaxf(sqrtf(s), 1e-12f);
        }
        rnorm_s[tid] = v;
    }
    __syncthreads();

    // ---- fused epilogue: normalize, sigmoid-gate, pool, max, diag maps
    float mx[4], sw[4], swa[4];
    #pragma unroll
    for (int mt = 0; mt < 4; mt++) { mx[mt] = -1e30f; sw[mt] = 0.f; swa[mt] = 0.f; }
    float s1n = 0.f, s1d = 0.f, s2n = 0.f, s2d = 0.f;
    const int dmt = (n >> 4) & 3, dq = n >> 6, dl = n & 15;
    const bool isdiag = (q == dq) && ((l & 15) == dl);

    #pragma unroll
    for (int ht = 0; ht < 7; ht++) {
        if (ht < HT) {
            int rowb = hh * 112 + ht * 16 + ((l >> 4) << 2);
            #pragma unroll
            for (int r = 0; r < 4; r++) {
                int hw = rowb + r;
                float rn = rnorm_s[hw];
                bool valid = hw < 196;
                #pragma unroll
                for (int mt = 0; mt < 4; mt++) {
                    float a0 = acc[ht][mt][r] * rn;
                    if (valid) {
                        float wg = 1.0f / (1.0f + __expf((0.65f - a0) * (1.0f / 0.03f)));
                        mx[mt]  = fmaxf(mx[mt], a0);
                        sw[mt] += wg;
                        swa[mt] += wg * a0;
                        if (isdiag && mt == dmt) {
                            out[n * 196 + hw] = a0;                 // A
                            out[116224 + n * 196 + hw] = wg;        // Pos
                            float p2 = 1.0f / (1.0f + __expf((0.40f - a0) * (1.0f / 0.03f)));
                            float ng = 1.0f - p2;
                            out[166400 + n * 196 + hw] = ng;        // Neg
                            s1n += wg * a0; s1d += wg;
                            s2n += ng * a0; s2d += ng;
                        }
                    }
                }
            }
        }
    }

    // cross-lane reduce (row-groups 16 apart hold same m)
    #pragma unroll
    for (int mt = 0; mt < 4; mt++) {
        float m1 = mx[mt], v1 = sw[mt], v2 = swa[mt];
        m1 = fmaxf(m1, __shfl_xor(m1, 16, 64)); v1 += __shfl_xor(v1, 16, 64); v2 += __shfl_xor(v2, 16, 64);
        m1 = fmaxf(m1, __shfl_xor(m1, 32, 64)); v1 += __shfl_xor(v1, 32, 64); v2 += __shfl_xor(v2, 32, 64);
        if (l < 16) {
            int m = q * 64 + mt * 16 + l;
            red_max[hh][m] = m1; red_sw[hh][m] = v1; red_swa[hh][m] = v2;
        }
    }
    if (isdiag) {
        diag_parts[hh][l >> 4][0] = s1n;
        diag_parts[hh][l >> 4][1] = s1d;
        diag_parts[hh][l >> 4][2] = s2n;
        diag_parts[hh][l >> 4][3] = s2d;
    }
    __syncthreads();

    if (tid < 256) {
        int m = tid;
        float mxv = fmaxf(red_max[0][m], red_max[1][m]);
        float num = red_swa[0][m] + red_swa[1][m];
        float den = red_sw[0][m] + red_sw[1][m];
        float sim = num / den;
        if (m == n) sim *= -99.0f;
        out[50176 + n * 258 + 1 + m] = sim * RLT;
        out[216576 + n * 256 + m] = mxv;
        if (m == n) {
            float t1n = 0.f, t1d = 0.f, t2n = 0.f, t2d = 0.f;
            #pragma unroll
            for (int h2 = 0; h2 < 2; h2++)
                #pragma unroll
                for (int g = 0; g < 4; g++) {
                    t1n += diag_parts[h2][g][0]; t1d += diag_parts[h2][g][1];
                    t2n += diag_parts[h2][g][2]; t2d += diag_parts[h2][g][3];
                }
            out[50176 + n * 258]       = (t1n / t1d) * RLT;
            out[50176 + n * 258 + 257] = (t2n / t2d) * RLT;
        }
    }
}

extern "C" void kernel_launch(void* const* d_in, const int* in_sizes, int n_in,
                              void* d_out, int out_size, void* d_ws, size_t ws_size,
                              hipStream_t stream) {
    const float* img = (const float*)d_in[0];
    const float* aud = (const float*)d_in[1];
    float* out = (float*)d_out;
    _Float16* aud_pk = (_Float16*)d_ws;   // 512*256 fp16 = 256 KB

    prep_aud_pk<<<256, 256, 0, stream>>>(aud, aud_pk);
    av_mfma<<<256, 512, 0, stream>>>(img, aud_pk, out);
}